// Round 21
// baseline (60.436 us; speedup 1.0000x reference)
//
#include <hip/hip_runtime.h>
#include <math.h>

#define LWT 512
#define NWT 64
#define BB 4
#define SBASE 16
#define BLK 32
#define HALO 36

// ws layout (floats): sarr [0,BT) | wtP [+65536 (512*64 float2)) | s1g | s2g

// XLA algsimp: x/44100 -> x * RN32(1/44100); *512 folds exactly (pow2), so
// increment = RN32(p * C), C = RN32(512/44100). asm barrier forces the product
// to be ROUNDED before the consuming add (blocks -ffp-contract=fast fusion).
#define INC_C ((float)(512.0 / 44100.0))

__device__ __forceinline__ float inc_mul(float p) {
  float v = p * INC_C;
  asm volatile("" : "+v"(v));
  return v;
}
__device__ __forceinline__ float inc_of(const float* p, int t) { return inc_mul(p[t]); }

__device__ __forceinline__ float2 wt_at2(const float2* wtP, unsigned byteoff) {
  return *reinterpret_cast<const float2*>(reinterpret_cast<const char*>(wtP) + byteoff);
}

// ---- Kernel A: level-0 local scans (fully parallel) + folded wtP build ----
// wtP[c][n] = (wt[n][c], RN(wt[n][(c+1)&511] - wt[n][c])): the same subtraction
// r16 performed per-use; value/bit-identical downstream.
__global__ void __launch_bounds__(256) scan_level0(const float* __restrict__ pitch,
                                                   float* __restrict__ sarr,
                                                   float* __restrict__ s1g,
                                                   const float* __restrict__ wt,
                                                   float2* __restrict__ wtP,
                                                   int T, int NB1) {
  if (blockIdx.y == BB) {  // folded wtP build row
    int idx = blockIdx.x * blockDim.x + threadIdx.x;
    if (idx < NWT * LWT) {
      int n = idx >> 9, c = idx & 511;        // consecutive c: coalesced reads
      float lo = wt[n * 512 + c];
      float hi = wt[n * 512 + ((c + 1) & 511)];
      wtP[c * NWT + n] = make_float2(lo, hi - lo);
    }
    return;
  }
  int k = blockIdx.x * blockDim.x + threadIdx.x;
  int b = blockIdx.y;
  if (k >= NB1) return;
  const float* prow = pitch + (size_t)b * T;
  float* srow = sarr + (size_t)b * T;
  int t0 = k * SBASE;
  float run = 0.0f;
  if (t0 + SBASE <= T) {
    const float4* p4 = reinterpret_cast<const float4*>(prow + t0);
    float4* s4o = reinterpret_cast<float4*>(srow + t0);
#pragma unroll
    for (int i = 0; i < 4; ++i) {
      float4 v = p4[i];
      float4 o;
      run += inc_mul(v.x); o.x = run;
      run += inc_mul(v.y); o.y = run;
      run += inc_mul(v.z); o.z = run;
      run += inc_mul(v.w); o.w = run;
      s4o[i] = o;
    }
  } else {
    for (int t = t0; t < T; ++t) { run += inc_of(prow, t); srow[t] = run; }
  }
  s1g[(size_t)b * NB1 + k] = run;
}

// ---- Kernel B: merged level-1 scan + levels 2..4 + combine (1 block/row) ----
__global__ void __launch_bounds__(1024) scan_mid(float* __restrict__ s1g,
                                                 float* __restrict__ s2g,
                                                 int NB1, int NB2) {
  int b = blockIdx.x, tid = threadIdx.x;
  float* s1r = s1g + (size_t)b * NB1;
  __shared__ float s2[544];
  __shared__ float s3[48];
  __shared__ float s4[16];
  const int NB3 = (NB2 + SBASE - 1) / SBASE;  // 33
  const int NB4 = (NB3 + SBASE - 1) / SBASE;  // 3
  if (tid < NB2) {
    int a0 = tid * SBASE, a1 = a0 + SBASE < NB1 ? a0 + SBASE : NB1;
    float run = 0.0f;
    for (int a = a0; a < a1; ++a) { run += s1r[a]; s1r[a] = run; }
    s2[tid] = run;
  }
  __syncthreads();
  if (tid < NB3) {
    int a0 = tid * SBASE, a1 = a0 + SBASE < NB2 ? a0 + SBASE : NB2;
    float run = 0.0f;
    for (int a = a0; a < a1; ++a) { run += s2[a]; s2[a] = run; }
    s3[tid] = run;
  }
  __syncthreads();
  if (tid < NB4) {
    int a0 = tid * SBASE, a1 = a0 + SBASE < NB3 ? a0 + SBASE : NB3;
    float run = 0.0f;
    for (int a = a0; a < a1; ++a) { run += s3[a]; s3[a] = run; }
    s4[tid] = run;
  }
  __syncthreads();
  if (tid == 0) { float r = 0.0f; for (int a = 0; a < NB4; ++a) { r += s4[a]; s4[a] = r; } }
  __syncthreads();
  if (tid < NB3 && tid >= SBASE) s3[tid] = s3[tid] + s4[tid / SBASE - 1];
  __syncthreads();
  if (tid < NB2) {
    float v = s2[tid];
    if (tid >= SBASE) v = v + s3[tid / SBASE - 1];
    s2g[(size_t)b * NB2 + tid] = v;
  }
}

// Wave64 reduction on the VALU pipe (DPP): xor1, xor2 (quad_perm),
// row_half_mirror, row_mirror, bcast15 (rows 1&3), bcast31 (rows 2&3);
// full sum in lanes 48-63; readlane(63) broadcasts.
__device__ __forceinline__ float dpp_reduce_add(float x) {
  x += __int_as_float(__builtin_amdgcn_update_dpp(0, __float_as_int(x), 0xB1, 0xf, 0xf, true));
  x += __int_as_float(__builtin_amdgcn_update_dpp(0, __float_as_int(x), 0x4E, 0xf, 0xf, true));
  x += __int_as_float(__builtin_amdgcn_update_dpp(0, __float_as_int(x), 0x141, 0xf, 0xf, true));
  x += __int_as_float(__builtin_amdgcn_update_dpp(0, __float_as_int(x), 0x140, 0xf, 0xf, true));
  x += __int_as_float(__builtin_amdgcn_update_dpp(0, __float_as_int(x), 0x142, 0xa, 0xf, true));
  x += __int_as_float(__builtin_amdgcn_update_dpp(0, __float_as_int(x), 0x143, 0xc, 0xf, true));
  return __int_as_float(__builtin_amdgcn_readlane(__float_as_int(x), 63));
}

// ---- Fused (r16 structure): s1-combine + idx + att_pre + conv + softmax ----
// BLK=32, ~12 KB LDS. Stage A stores byte offsets il*512 into wtP; every
// gather is one dwordx2 (lo, slope); wv = fmaf(alpha, slope, lo) -- the same
// sub+fma bits as r16's lo + alpha*(hi-lo).
__global__ void __launch_bounds__(256) fused_out(
    const float* __restrict__ pitch, const float* __restrict__ sarr,
    const float* __restrict__ s1g, const float* __restrict__ s2g,
    const float* __restrict__ y, const float* __restrict__ amp,
    const float2* __restrict__ wtP, const float* __restrict__ cw,
    const float* __restrict__ cb, float* __restrict__ out,
    int T, int NB1, int NB2) {
  __shared__ float lds_att[HALO][64];     // 9.2 KB
  __shared__ unsigned ilo_l[BB][HALO];    // byte offset il*512
  __shared__ float alf_l[BB][HALO];
  __shared__ float y_l[BB][HALO];
  __shared__ float amp_l[BB][HALO];
  __shared__ float out_l[BB][BLK + 1];    // +1 pad: conflict-free 4-lane store
  int t0 = blockIdx.x * BLK;
  int wid = threadIdx.x >> 6, lane = threadIdx.x & 63;
  unsigned lane8 = (unsigned)lane << 3;

  // ---- Stage A: wave = batch b, lane = halo index ----
  {
    int b = wid;
    for (int i = lane; i < HALO; i += 64) {
      int t = t0 - 2 + i;
      if (t >= 0 && t < T) {
        float S = sarr[(size_t)b * T + t];
        if (t >= SBASE) {
          int k1 = (t >> 4) - 1;
          float s1v = s1g[b * NB1 + k1];
          if (k1 >= SBASE) s1v = s1v + s2g[b * NB2 + (k1 >> 4) - 1];  // ref combine
          S = S + s1v;
        }
        float iv = S - inc_of(pitch, t);   // row-0 increment, folded constant
        // exact mod 512 (== fmodf+fixup bits; q exact pow2 scale, one fma rnd)
        float q = iv * (1.0f / 512.0f);
        float k = floorf(q);
        iv = fmaf(-k, 512.0f, iv);
        float fl = floorf(iv);
        float alpha = iv - fl;              // exact (Sterbenz)
        int ili = (int)fl; if (ili > 511) ili = 511;   // jnp.take clip (alpha==0 there)
        ilo_l[b][i] = (unsigned)ili << 9;   // *64 pairs * 8B
        alf_l[b][i] = alpha;
        y_l[b][i] = y[(size_t)b * T + t];
        amp_l[b][i] = amp[(size_t)b * T + t];
      }
    }
  }
  __syncthreads();

  // ---- Stage B: att_pre ----
  for (int i = wid; i < HALO; i += 4) {
    int t = t0 - 2 + i;
    float acc = 0.0f;
    if (t >= 0 && t < T) {
#pragma unroll
      for (int b = 0; b < BB; ++b) {
        float2 p = wt_at2(wtP, ilo_l[b][i] + lane8);
        float wv = fmaf(alf_l[b][i], p.y, p.x);
        acc += wv * y_l[b][i];
      }
      acc *= 0.25f;  // mean over batch
    }
    lds_att[i][lane] = acc;
  }
  __syncthreads();

  float w0 = cw[0], w1 = cw[1], w2 = cw[2], w3 = cw[3], w4 = cw[4];
  float bias = cb[0];
#pragma unroll 4
  for (int i = wid; i < BLK; i += 4) {
    int t = t0 + i;
    if (t >= T) continue;  // wave-uniform
    float c = bias + lds_att[i][lane] * w0 + lds_att[i + 1][lane] * w1 +
              lds_att[i + 2][lane] * w2 + lds_att[i + 3][lane] * w3 +
              lds_att[i + 4][lane] * w4;
    float e = __expf(c);   // no max-subtract (shift-invariant, c bounded)
    float2 p0 = wt_at2(wtP, ilo_l[0][i + 2] + lane8);
    float2 p1 = wt_at2(wtP, ilo_l[1][i + 2] + lane8);
    float2 p2 = wt_at2(wtP, ilo_l[2][i + 2] + lane8);
    float2 p3 = wt_at2(wtP, ilo_l[3][i + 2] + lane8);
    float r0 = e * fmaf(alf_l[0][i + 2], p0.y, p0.x);
    float r1 = e * fmaf(alf_l[1][i + 2], p1.y, p1.x);
    float r2 = e * fmaf(alf_l[2][i + 2], p2.y, p2.x);
    float r3 = e * fmaf(alf_l[3][i + 2], p3.y, p3.x);
    // 5 VALU-pipe DPP reductions (independent chains)
    float s0 = dpp_reduce_add(r0);
    float s1_ = dpp_reduce_add(r1);
    float s2_ = dpp_reduce_add(r2);
    float s3_ = dpp_reduce_add(r3);
    float ssum = dpp_reduce_add(e);
#if __has_builtin(__builtin_amdgcn_rcpf)
    float rc = __builtin_amdgcn_rcpf(ssum);
#else
    float rc = 1.0f / ssum;
#endif
    if (lane < BB) {
      float pv = lane == 0 ? s0 : lane == 1 ? s1_ : lane == 2 ? s2_ : s3_;
      out_l[lane][i] = pv * rc * amp_l[lane][i + 2];
    }
  }
  __syncthreads();

  // ---- Epilogue: coalesced stores (wave = batch, lanes 0..BLK-1) ----
  {
    int b = wid;
    int t = t0 + lane;
    if (lane < BLK && t < T) out[(size_t)b * T + t] = out_l[b][lane];
  }
}

extern "C" void kernel_launch(void* const* d_in, const int* in_sizes, int n_in,
                              void* d_out, int out_size, void* d_ws, size_t ws_size,
                              hipStream_t stream) {
  const float* pitch = (const float*)d_in[0];
  const float* amp   = (const float*)d_in[1];
  const float* y     = (const float*)d_in[2];
  const float* wt    = (const float*)d_in[3];
  const float* cw    = (const float*)d_in[4];
  const float* cb    = (const float*)d_in[5];
  float* out = (float*)d_out;

  int BT = in_sizes[2];   // B*T
  int T = BT / BB;        // 132300
  int NB1 = (T + SBASE - 1) / SBASE;    // 8269
  int NB2 = (NB1 + SBASE - 1) / SBASE;  // 517

  float* ws   = (float*)d_ws;
  float* sarr = ws;
  float2* wtP = (float2*)(ws + (size_t)BT);
  float* s1g  = ws + (size_t)BT + 2 * NWT * LWT;
  float* s2g  = s1g + (size_t)BB * NB1;

  hipLaunchKernelGGL(scan_level0, dim3(128, BB + 1), dim3(256), 0, stream,
                     pitch, sarr, s1g, wt, wtP, T, NB1);
  hipLaunchKernelGGL(scan_mid, dim3(BB), dim3(1024), 0, stream, s1g, s2g, NB1, NB2);
  hipLaunchKernelGGL(fused_out, dim3((T + BLK - 1) / BLK), dim3(256), 0, stream,
                     pitch, sarr, s1g, s2g, y, amp, wtP, cw, cb, out, T, NB1, NB2);
}

// Round 22
// 54.050 us; speedup vs baseline: 1.1181x; 1.1181x over previous
//
#include <hip/hip_runtime.h>
#include <math.h>

#define LWT 512
#define NWT 64
#define BB 4
#define SBASE 16
#define BLK 32
#define HALO 36

// ws layout (floats): sarr [0,BT) | wtT [+32768) | s1g [+4*8320) | s2g [+4*544)

// XLA algsimp: x/44100 -> x * RN32(1/44100); *512 folds exactly (pow2), so
// increment = RN32(p * C), C = RN32(512/44100). asm barrier forces the product
// to be ROUNDED before the consuming add (blocks -ffp-contract=fast fusion).
#define INC_C ((float)(512.0 / 44100.0))

__device__ __forceinline__ float inc_mul(float p) {
  float v = p * INC_C;
  asm volatile("" : "+v"(v));
  return v;
}
__device__ __forceinline__ float inc_of(const float* p, int t) { return inc_mul(p[t]); }

// saddr-form load: uniform SGPR base + 32-bit per-lane byte offset (1 v_add).
__device__ __forceinline__ float wt_at(const float* wtT, unsigned byteoff) {
  return *reinterpret_cast<const float*>(reinterpret_cast<const char*>(wtT) + byteoff);
}

// ---- Kernel A: level-0 local scans (fully parallel) + folded wt transpose ----
__global__ void __launch_bounds__(256) scan_level0(const float* __restrict__ pitch,
                                                   float* __restrict__ sarr,
                                                   float* __restrict__ s1g,
                                                   const float* __restrict__ wt,
                                                   float* __restrict__ wtT,
                                                   int T, int NB1) {
  if (blockIdx.y == BB) {  // folded transpose row
    int i = blockIdx.x * blockDim.x + threadIdx.x;
    if (i < NWT * LWT) {
      int n = i >> 9, c = i & 511;
      wtT[c * NWT + n] = wt[i];
    }
    return;
  }
  int k = blockIdx.x * blockDim.x + threadIdx.x;
  int b = blockIdx.y;
  if (k >= NB1) return;
  const float* prow = pitch + (size_t)b * T;
  float* srow = sarr + (size_t)b * T;
  int t0 = k * SBASE;
  float run = 0.0f;
  if (t0 + SBASE <= T) {
    const float4* p4 = reinterpret_cast<const float4*>(prow + t0);
    float4* s4o = reinterpret_cast<float4*>(srow + t0);
#pragma unroll
    for (int i = 0; i < 4; ++i) {
      float4 v = p4[i];
      float4 o;
      run += inc_mul(v.x); o.x = run;
      run += inc_mul(v.y); o.y = run;
      run += inc_mul(v.z); o.z = run;
      run += inc_mul(v.w); o.w = run;
      s4o[i] = o;
    }
  } else {
    for (int t = t0; t < T; ++t) { run += inc_of(prow, t); srow[t] = run; }
  }
  s1g[(size_t)b * NB1 + k] = run;
}

// ---- Kernel B: merged level-1 scan + levels 2..4 + combine (1 block/row) ----
// Bit-identical to the r16 scan pair (verified r21: absmax 3.814697e-06).
__global__ void __launch_bounds__(1024) scan_mid(float* __restrict__ s1g,
                                                 float* __restrict__ s2g,
                                                 int NB1, int NB2) {
  int b = blockIdx.x, tid = threadIdx.x;
  float* s1r = s1g + (size_t)b * NB1;
  __shared__ float s2[544];
  __shared__ float s3[48];
  __shared__ float s4[16];
  const int NB3 = (NB2 + SBASE - 1) / SBASE;  // 33
  const int NB4 = (NB3 + SBASE - 1) / SBASE;  // 3
  if (tid < NB2) {
    int a0 = tid * SBASE, a1 = a0 + SBASE < NB1 ? a0 + SBASE : NB1;
    float run = 0.0f;
    for (int a = a0; a < a1; ++a) { run += s1r[a]; s1r[a] = run; }
    s2[tid] = run;
  }
  __syncthreads();
  if (tid < NB3) {
    int a0 = tid * SBASE, a1 = a0 + SBASE < NB2 ? a0 + SBASE : NB2;
    float run = 0.0f;
    for (int a = a0; a < a1; ++a) { run += s2[a]; s2[a] = run; }
    s3[tid] = run;
  }
  __syncthreads();
  if (tid < NB4) {
    int a0 = tid * SBASE, a1 = a0 + SBASE < NB3 ? a0 + SBASE : NB3;
    float run = 0.0f;
    for (int a = a0; a < a1; ++a) { run += s3[a]; s3[a] = run; }
    s4[tid] = run;
  }
  __syncthreads();
  if (tid == 0) { float r = 0.0f; for (int a = 0; a < NB4; ++a) { r += s4[a]; s4[a] = r; } }
  __syncthreads();
  if (tid < NB3 && tid >= SBASE) s3[tid] = s3[tid] + s4[tid / SBASE - 1];
  __syncthreads();
  if (tid < NB2) {
    float v = s2[tid];
    if (tid >= SBASE) v = v + s3[tid / SBASE - 1];
    s2g[(size_t)b * NB2 + tid] = v;
  }
}

// Wave64 reduction on the VALU pipe (DPP): xor1, xor2 (quad_perm),
// row_half_mirror, row_mirror, bcast15 (rows 1&3), bcast31 (rows 2&3);
// full sum in lanes 48-63; readlane(63) broadcasts.
__device__ __forceinline__ float dpp_reduce_add(float x) {
  x += __int_as_float(__builtin_amdgcn_update_dpp(0, __float_as_int(x), 0xB1, 0xf, 0xf, true));
  x += __int_as_float(__builtin_amdgcn_update_dpp(0, __float_as_int(x), 0x4E, 0xf, 0xf, true));
  x += __int_as_float(__builtin_amdgcn_update_dpp(0, __float_as_int(x), 0x141, 0xf, 0xf, true));
  x += __int_as_float(__builtin_amdgcn_update_dpp(0, __float_as_int(x), 0x140, 0xf, 0xf, true));
  x += __int_as_float(__builtin_amdgcn_update_dpp(0, __float_as_int(x), 0x142, 0xa, 0xf, true));
  x += __int_as_float(__builtin_amdgcn_update_dpp(0, __float_as_int(x), 0x143, 0xc, 0xf, true));
  return __int_as_float(__builtin_amdgcn_readlane(__float_as_int(x), 63));
}

// ---- Fused (r16 structure, byte-exact): s1-combine + idx + att_pre + conv +
// softmax + einsum. BLK=32, 12.6 KB LDS -> wave-capped occupancy. Stage A
// stores PRE-SCALED byte offsets (il<<8): every wtT access = 1 v_add + load.
__global__ void __launch_bounds__(256) fused_out(
    const float* __restrict__ pitch, const float* __restrict__ sarr,
    const float* __restrict__ s1g, const float* __restrict__ s2g,
    const float* __restrict__ y, const float* __restrict__ amp,
    const float* __restrict__ wtT, const float* __restrict__ cw,
    const float* __restrict__ cb, float* __restrict__ out,
    int T, int NB1, int NB2) {
  __shared__ float lds_att[HALO][64];     // 9.2 KB
  __shared__ unsigned ilo_l[BB][HALO];    // byte offset il*256
  __shared__ unsigned ihi_l[BB][HALO];    // byte offset ih*256
  __shared__ float alf_l[BB][HALO];
  __shared__ float y_l[BB][HALO];
  __shared__ float amp_l[BB][HALO];
  __shared__ float out_l[BB][BLK + 1];    // +1 pad: conflict-free 4-lane store
  int t0 = blockIdx.x * BLK;
  int wid = threadIdx.x >> 6, lane = threadIdx.x & 63;
  unsigned lane4 = (unsigned)lane << 2;

  // ---- Stage A: wave = batch b, lane = halo index ----
  {
    int b = wid;
    for (int i = lane; i < HALO; i += 64) {
      int t = t0 - 2 + i;
      if (t >= 0 && t < T) {
        float S = sarr[(size_t)b * T + t];
        if (t >= SBASE) {
          int k1 = (t >> 4) - 1;
          float s1v = s1g[b * NB1 + k1];
          if (k1 >= SBASE) s1v = s1v + s2g[b * NB2 + (k1 >> 4) - 1];  // ref combine
          S = S + s1v;
        }
        float iv = S - inc_of(pitch, t);   // row-0 increment, folded constant
        // exact mod 512 (== fmodf+fixup bits; q exact pow2 scale, one fma rnd)
        float q = iv * (1.0f / 512.0f);
        float k = floorf(q);
        iv = fmaf(-k, 512.0f, iv);
        float fl = floorf(iv);
        float alpha = iv - fl;              // exact (Sterbenz)
        int ili = (int)fl; if (ili > 511) ili = 511;   // jnp.take clip
        int ihi = ((int)ceilf(iv)) & 511;              // ceil 512 wraps to 0
        ilo_l[b][i] = (unsigned)ili << 8;   // *NWT(64) * 4B
        ihi_l[b][i] = (unsigned)ihi << 8;
        alf_l[b][i] = alpha;
        y_l[b][i] = y[(size_t)b * T + t];
        amp_l[b][i] = amp[(size_t)b * T + t];
      }
    }
  }
  __syncthreads();

  // ---- Stage B: att_pre ----
  for (int i = wid; i < HALO; i += 4) {
    int t = t0 - 2 + i;
    float acc = 0.0f;
    if (t >= 0 && t < T) {
#pragma unroll
      for (int b = 0; b < BB; ++b) {
        float lo = wt_at(wtT, ilo_l[b][i] + lane4);
        float hi = wt_at(wtT, ihi_l[b][i] + lane4);
        float alpha = alf_l[b][i];
        acc += (lo + alpha * (hi - lo)) * y_l[b][i];
      }
      acc *= 0.25f;  // mean over batch
    }
    lds_att[i][lane] = acc;
  }
  __syncthreads();

  float w0 = cw[0], w1 = cw[1], w2 = cw[2], w3 = cw[3], w4 = cw[4];
  float bias = cb[0];
#pragma unroll 4
  for (int i = wid; i < BLK; i += 4) {
    int t = t0 + i;
    if (t >= T) continue;  // wave-uniform
    float c = bias + lds_att[i][lane] * w0 + lds_att[i + 1][lane] * w1 +
              lds_att[i + 2][lane] * w2 + lds_att[i + 3][lane] * w3 +
              lds_att[i + 4][lane] * w4;
    float e = __expf(c);   // no max-subtract (shift-invariant, c bounded)
    float r0, r1, r2, r3;
    {
      float lo = wt_at(wtT, ilo_l[0][i + 2] + lane4);
      float hi = wt_at(wtT, ihi_l[0][i + 2] + lane4);
      r0 = e * (lo + alf_l[0][i + 2] * (hi - lo));
    }
    {
      float lo = wt_at(wtT, ilo_l[1][i + 2] + lane4);
      float hi = wt_at(wtT, ihi_l[1][i + 2] + lane4);
      r1 = e * (lo + alf_l[1][i + 2] * (hi - lo));
    }
    {
      float lo = wt_at(wtT, ilo_l[2][i + 2] + lane4);
      float hi = wt_at(wtT, ihi_l[2][i + 2] + lane4);
      r2 = e * (lo + alf_l[2][i + 2] * (hi - lo));
    }
    {
      float lo = wt_at(wtT, ilo_l[3][i + 2] + lane4);
      float hi = wt_at(wtT, ihi_l[3][i + 2] + lane4);
      r3 = e * (lo + alf_l[3][i + 2] * (hi - lo));
    }
    // 5 VALU-pipe DPP reductions (independent chains)
    float s0 = dpp_reduce_add(r0);
    float s1_ = dpp_reduce_add(r1);
    float s2_ = dpp_reduce_add(r2);
    float s3_ = dpp_reduce_add(r3);
    float ssum = dpp_reduce_add(e);
#if __has_builtin(__builtin_amdgcn_rcpf)
    float rc = __builtin_amdgcn_rcpf(ssum);
#else
    float rc = 1.0f / ssum;
#endif
    if (lane < BB) {
      float pv = lane == 0 ? s0 : lane == 1 ? s1_ : lane == 2 ? s2_ : s3_;
      out_l[lane][i] = pv * rc * amp_l[lane][i + 2];
    }
  }
  __syncthreads();

  // ---- Epilogue: coalesced stores (wave = batch, lanes 0..BLK-1) ----
  {
    int b = wid;
    int t = t0 + lane;
    if (lane < BLK && t < T) out[(size_t)b * T + t] = out_l[b][lane];
  }
}

extern "C" void kernel_launch(void* const* d_in, const int* in_sizes, int n_in,
                              void* d_out, int out_size, void* d_ws, size_t ws_size,
                              hipStream_t stream) {
  const float* pitch = (const float*)d_in[0];
  const float* amp   = (const float*)d_in[1];
  const float* y     = (const float*)d_in[2];
  const float* wt    = (const float*)d_in[3];
  const float* cw    = (const float*)d_in[4];
  const float* cb    = (const float*)d_in[5];
  float* out = (float*)d_out;

  int BT = in_sizes[2];   // B*T
  int T = BT / BB;        // 132300
  int NB1 = (T + SBASE - 1) / SBASE;    // 8269
  int NB2 = (NB1 + SBASE - 1) / SBASE;  // 517

  float* ws   = (float*)d_ws;
  float* sarr = ws;
  float* wtT  = ws + (size_t)BT;
  float* s1g  = ws + (size_t)BT + NWT * LWT;
  float* s2g  = s1g + (size_t)BB * NB1;

  hipLaunchKernelGGL(scan_level0, dim3(128, BB + 1), dim3(256), 0, stream,
                     pitch, sarr, s1g, wt, wtT, T, NB1);
  hipLaunchKernelGGL(scan_mid, dim3(BB), dim3(1024), 0, stream, s1g, s2g, NB1, NB2);
  hipLaunchKernelGGL(fused_out, dim3((T + BLK - 1) / BLK), dim3(256), 0, stream,
                     pitch, sarr, s1g, s2g, y, amp, wtT, cw, cb, out, T, NB1, NB2);
}